// Round 1
// baseline (399.230 us; speedup 1.0000x reference)
//
#include <hip/hip_runtime.h>
#include <hip/hip_bf16.h>

typedef unsigned short u16;
typedef __bf16 bf16x8 __attribute__((ext_vector_type(8)));
typedef float f32x4 __attribute__((ext_vector_type(4)));

static __device__ __forceinline__ u16 f2b(float f) {
    __hip_bfloat16 h = __float2bfloat16(f);
    union { __hip_bfloat16 b; u16 u; } c;
    c.b = h;
    return c.u;
}

// fp32 -> bf16 bits, 8 elements per thread-iter (16B read x2, 16B write)
__global__ void cvt_f32_to_bf16(const float* __restrict__ in, u16* __restrict__ out, long n8) {
    long i = (long)blockIdx.x * blockDim.x + threadIdx.x;
    long stride = (long)gridDim.x * blockDim.x;
    for (long v = i; v < n8; v += stride) {
        const float4* p = reinterpret_cast<const float4*>(in) + 2 * v;
        float4 a = p[0];
        float4 b = p[1];
        uint4 o;
        o.x = (unsigned)f2b(a.x) | ((unsigned)f2b(a.y) << 16);
        o.y = (unsigned)f2b(a.z) | ((unsigned)f2b(a.w) << 16);
        o.z = (unsigned)f2b(b.x) | ((unsigned)f2b(b.y) << 16);
        o.w = (unsigned)f2b(b.z) | ((unsigned)f2b(b.w) << 16);
        reinterpret_cast<uint4*>(out)[v] = o;
    }
}

// W[K][N] fp32 -> Wt[N][K] bf16 bits, 32x32 LDS-tiled transpose (+1 pad, no bank conflicts)
__global__ void transpose_cvt(const float* __restrict__ w, u16* __restrict__ wt, int K, int N) {
    __shared__ float tile[32][33];
    int bn = blockIdx.x * 32;
    int bk = blockIdx.y * 32;
    int tx = threadIdx.x & 31;
    int ty = threadIdx.x >> 5;   // 0..7
#pragma unroll
    for (int i = 0; i < 32; i += 8)
        tile[ty + i][tx] = w[(long)(bk + ty + i) * N + bn + tx];
    __syncthreads();
#pragma unroll
    for (int i = 0; i < 32; i += 8)
        wt[(long)(bn + ty + i) * K + bk + tx] = f2b(tile[tx][ty + i]);
}

static __device__ __forceinline__ void gl_lds16(const u16* g, u16* l) {
    __builtin_amdgcn_global_load_lds(
        (const __attribute__((address_space(1))) void*)g,
        (__attribute__((address_space(3))) void*)l, 16, 0, 0);
}

// m97-structure bf16 GEMM: C[M][N] = A[M][K] * Wt[N][K]^T
// 128x128 tile, BK=32, 256 threads = 4 waves (2x2), 64x64 per wave,
// global_load_lds width=16 staging, 16x16x32 bf16 MFMA, acc[4][4] f32x4.
__global__ __launch_bounds__(256) void gemm_bf16_128(
    const u16* __restrict__ A, const u16* __restrict__ Bt,
    float* __restrict__ C, int M, int N, int K) {
    __shared__ u16 As[128 * 32];
    __shared__ u16 Bs[128 * 32];

    const int t = threadIdx.x;
    const int lane = t & 63;
    const int w = t >> 6;        // wave 0..3
    const int wr = w >> 1;       // wave row 0..1
    const int wc = w & 1;        // wave col 0..1

    const int ntn = N >> 7;                  // tiles along N
    const int tm = blockIdx.x / ntn;
    const int tn = blockIdx.x % ntn;
    const long arow0 = (long)tm * 128;
    const long bcol0 = (long)tn * 128;

    // staging: thread t loads 16B at linear tile byte offset t*16 (+4096 per issue)
    const int r_a = t >> 2;          // tile row 0..63 (first issue)
    const int cofs = (t & 3) * 8;    // u16 offset within 32-elem row
    const u16* Ag0 = A + (arow0 + r_a) * K + cofs;
    const u16* Ag1 = Ag0 + (long)64 * K;
    const u16* Bg0 = Bt + (bcol0 + r_a) * K + cofs;
    const u16* Bg1 = Bg0 + (long)64 * K;
    u16* AsD0 = &As[t * 8];
    u16* AsD1 = AsD0 + 2048;
    u16* BsD0 = &Bs[t * 8];
    u16* BsD1 = BsD0 + 2048;

    // fragment read coords (A: row=lane&15, k=(lane>>4)*8; B: col=lane&15, same k)
    const int fr = lane & 15;
    const int fk = (lane >> 4) * 8;

    f32x4 acc[4][4] = {};

    for (int kt = 0; kt < K; kt += 32) {
        __syncthreads();   // previous tile fully consumed
        gl_lds16(Ag0 + kt, AsD0);
        gl_lds16(Ag1 + kt, AsD1);
        gl_lds16(Bg0 + kt, BsD0);
        gl_lds16(Bg1 + kt, BsD1);
        __syncthreads();   // vmcnt(0) drain + barrier: tile resident

        bf16x8 af[4], bfr[4];
#pragma unroll
        for (int m = 0; m < 4; ++m)
            af[m] = *reinterpret_cast<const bf16x8*>(&As[(wr * 64 + m * 16 + fr) * 32 + fk]);
#pragma unroll
        for (int n = 0; n < 4; ++n)
            bfr[n] = *reinterpret_cast<const bf16x8*>(&Bs[(wc * 64 + n * 16 + fr) * 32 + fk]);

#pragma unroll
        for (int m = 0; m < 4; ++m)
#pragma unroll
            for (int n = 0; n < 4; ++n)
                acc[m][n] = __builtin_amdgcn_mfma_f32_16x16x32_bf16(af[m], bfr[n], acc[m][n], 0, 0, 0);
    }

    // C/D layout: col = lane&15, row = (lane>>4)*4 + j  [m89/m91 verified]
    const int crow = (lane >> 4) * 4;
    const int ccol = lane & 15;
#pragma unroll
    for (int m = 0; m < 4; ++m) {
#pragma unroll
        for (int n = 0; n < 4; ++n) {
            long r0 = arow0 + wr * 64 + m * 16 + crow;
            long c0 = bcol0 + wc * 64 + n * 16 + ccol;
#pragma unroll
            for (int j = 0; j < 4; ++j)
                C[(r0 + j) * N + c0] = acc[m][n][j];
        }
    }
}

// fallback (only if ws_size is too small): correct fp32 tiled GEMM
__global__ void gemm_f32_fallback(const float* __restrict__ A, const float* __restrict__ B,
                                  float* __restrict__ C, int M, int N, int K) {
    __shared__ float As[16][17];
    __shared__ float Bs[16][17];
    int tx = threadIdx.x & 15;
    int ty = threadIdx.x >> 4;
    int row = blockIdx.y * 16 + ty;
    int col = blockIdx.x * 16 + tx;
    float s = 0.f;
    for (int k0 = 0; k0 < K; k0 += 16) {
        As[ty][tx] = A[(long)row * K + k0 + tx];
        Bs[ty][tx] = B[(long)(k0 + ty) * N + col];
        __syncthreads();
#pragma unroll
        for (int kk = 0; kk < 16; ++kk) s += As[ty][kk] * Bs[kk][tx];
        __syncthreads();
    }
    C[(long)row * N + col] = s;
}

extern "C" void kernel_launch(void* const* d_in, const int* in_sizes, int n_in,
                              void* d_out, int out_size, void* d_ws, size_t ws_size,
                              hipStream_t stream) {
    const int M = 8192, K = 4096, N = 4096;
    const float* x = (const float*)d_in[0];       // [M][K] fp32
    const float* wte = (const float*)d_in[1];     // [K][N] fp32
    float* out = (float*)d_out;                   // [M][N] fp32

    const size_t need = (size_t)M * K * 2 + (size_t)K * N * 2;  // 96 MiB
    if (ws_size >= need) {
        u16* xb = (u16*)d_ws;                  // [M][K] bf16
        u16* wt = xb + (size_t)M * K;          // [N][K] bf16 (transposed)

        cvt_f32_to_bf16<<<2048, 256, 0, stream>>>(x, xb, (long)M * K / 8);

        dim3 tg(N / 32, K / 32);
        transpose_cvt<<<tg, 256, 0, stream>>>(wte, wt, K, N);

        const int nblocks = (M / 128) * (N / 128);   // 2048
        gemm_bf16_128<<<nblocks, 256, 0, stream>>>(xb, wt, out, M, N, K);
    } else {
        dim3 g(N / 16, M / 16);
        gemm_f32_fallback<<<g, 256, 0, stream>>>(x, wte, out, M, N, K);
    }
}

// Round 2
// 287.992 us; speedup vs baseline: 1.3863x; 1.3863x over previous
//
#include <hip/hip_runtime.h>
#include <hip/hip_bf16.h>

typedef unsigned short u16;
typedef __bf16 bf16x8 __attribute__((ext_vector_type(8)));
typedef float f32x4 __attribute__((ext_vector_type(4)));

static __device__ __forceinline__ u16 f2b(float f) {
    __hip_bfloat16 h = __float2bfloat16(f);
    union { __hip_bfloat16 b; u16 u; } c;
    c.b = h;
    return c.u;
}

// fp32 -> bf16 bits, 8 elements per thread-iter
__global__ void cvt_f32_to_bf16(const float* __restrict__ in, u16* __restrict__ out, long n8) {
    long i = (long)blockIdx.x * blockDim.x + threadIdx.x;
    long stride = (long)gridDim.x * blockDim.x;
    for (long v = i; v < n8; v += stride) {
        const float4* p = reinterpret_cast<const float4*>(in) + 2 * v;
        float4 a = p[0];
        float4 b = p[1];
        uint4 o;
        o.x = (unsigned)f2b(a.x) | ((unsigned)f2b(a.y) << 16);
        o.y = (unsigned)f2b(a.z) | ((unsigned)f2b(a.w) << 16);
        o.z = (unsigned)f2b(b.x) | ((unsigned)f2b(b.y) << 16);
        o.w = (unsigned)f2b(b.z) | ((unsigned)f2b(b.w) << 16);
        reinterpret_cast<uint4*>(out)[v] = o;
    }
}

// W[K][N] fp32 -> Wt[N][K] bf16 bits, 32x32 LDS-tiled transpose
__global__ void transpose_cvt(const float* __restrict__ w, u16* __restrict__ wt, int K, int N) {
    __shared__ float tile[32][33];
    int bn = blockIdx.x * 32;
    int bk = blockIdx.y * 32;
    int tx = threadIdx.x & 31;
    int ty = threadIdx.x >> 5;
#pragma unroll
    for (int i = 0; i < 32; i += 8)
        tile[ty + i][tx] = w[(long)(bk + ty + i) * N + bn + tx];
    __syncthreads();
#pragma unroll
    for (int i = 0; i < 32; i += 8)
        wt[(long)(bn + ty + i) * K + bk + tx] = f2b(tile[tx][ty + i]);
}

static __device__ __forceinline__ void gl_lds16(const u16* g, u16* l) {
    __builtin_amdgcn_global_load_lds(
        (const __attribute__((address_space(1))) void*)g,
        (__attribute__((address_space(3))) void*)l, 16, 0, 0);
}

// ---------------------------------------------------------------------------
// 256x256 8-phase bf16 GEMM (T1+T2+T3/T4+T5), C = A[8192][4096] * Wt[4096][4096]^T
// 512 threads = 8 waves (2M x 4N), per-wave 128x64 output, BK=64, K-tiles NT=64.
// LDS: 2 buf x (A[256][64] | B[256][64]) bf16 = 128 KiB, st_16x32 swizzle
// (colbyte ^= 32 when row&4), applied on pre-swizzled global src + ds_read addr.
// Staging: per phase 1 half-tile (2 x global_load_lds w16). A staged T+1,
// B staged T+2; boundary s_waitcnt vmcnt(4), vmcnt(0) only entering last tile.
// ---------------------------------------------------------------------------
#define GK 4096L

#define STG(srcbase, dstbase, hh, ktel)                                              \
    gl_lds16((srcbase) + (long)((hh) * 128) * GK + (ktel), (u16*)((dstbase) + (hh) * 16384)); \
    gl_lds16((srcbase) + (long)((hh) * 128 + 64) * GK + (ktel), (u16*)((dstbase) + (hh) * 16384 + 8192));

#define KTILE(CB, OB, SA, SB, VM, KTA, KTB) do {                                     \
    char* cb = shb + (CB) * 65536;                                                   \
    /* ---- phase 0: read A m0-3 + B n0-1 (12 ds), stage A-half0(T+1) ---- */        \
    _Pragma("unroll") for (int mi = 0; mi < 4; ++mi)                                 \
        _Pragma("unroll") for (int kk = 0; kk < 2; ++kk)                             \
            af[mi][kk] = *(const bf16x8*)(cb + aoff + mi * 2048 + kk * 64);          \
    _Pragma("unroll") for (int ni = 0; ni < 2; ++ni)                                 \
        _Pragma("unroll") for (int kk = 0; kk < 2; ++kk)                             \
            b01[ni][kk] = *(const bf16x8*)(cb + 32768 + boff + ni * 2048 + kk * 64); \
    if (SA) { STG(Asrc, ldsAt + (OB) * 65536, 0, KTA) }                              \
    __builtin_amdgcn_s_barrier();                                                    \
    asm volatile("s_waitcnt lgkmcnt(0)");                                            \
    __builtin_amdgcn_s_setprio(1);                                                   \
    _Pragma("unroll") for (int mi = 0; mi < 4; ++mi)                                 \
        _Pragma("unroll") for (int ni = 0; ni < 2; ++ni)                             \
            _Pragma("unroll") for (int kk = 0; kk < 2; ++kk)                         \
                acc[mi][ni] = __builtin_amdgcn_mfma_f32_16x16x32_bf16(af[mi][kk], b01[ni][kk], acc[mi][ni], 0, 0, 0); \
    __builtin_amdgcn_s_setprio(0);                                                   \
    __builtin_amdgcn_s_barrier();                                                    \
    /* ---- phase 1: read B n2-3 (4 ds), stage A-half1(T+1) ---- */                  \
    _Pragma("unroll") for (int ni = 0; ni < 2; ++ni)                                 \
        _Pragma("unroll") for (int kk = 0; kk < 2; ++kk)                             \
            b23[ni][kk] = *(const bf16x8*)(cb + 32768 + boff + (ni + 2) * 2048 + kk * 64); \
    if (SA) { STG(Asrc, ldsAt + (OB) * 65536, 1, KTA) }                              \
    __builtin_amdgcn_s_barrier();                                                    \
    asm volatile("s_waitcnt lgkmcnt(0)");                                            \
    __builtin_amdgcn_s_setprio(1);                                                   \
    _Pragma("unroll") for (int mi = 0; mi < 4; ++mi)                                 \
        _Pragma("unroll") for (int ni = 0; ni < 2; ++ni)                             \
            _Pragma("unroll") for (int kk = 0; kk < 2; ++kk)                         \
                acc[mi][ni + 2] = __builtin_amdgcn_mfma_f32_16x16x32_bf16(af[mi][kk], b23[ni][kk], acc[mi][ni + 2], 0, 0, 0); \
    __builtin_amdgcn_s_setprio(0);                                                   \
    __builtin_amdgcn_s_barrier();                                                    \
    /* ---- phase 2: read A m4-7 (8 ds), stage B-half0(T+2) ---- */                  \
    _Pragma("unroll") for (int mi = 0; mi < 4; ++mi)                                 \
        _Pragma("unroll") for (int kk = 0; kk < 2; ++kk)                             \
            af[mi][kk] = *(const bf16x8*)(cb + aoff + (mi + 4) * 2048 + kk * 64);    \
    if (SB) { STG(Bsrc, ldsBt + (CB) * 65536, 0, KTB) }                              \
    __builtin_amdgcn_s_barrier();                                                    \
    asm volatile("s_waitcnt lgkmcnt(0)");                                            \
    __builtin_amdgcn_s_setprio(1);                                                   \
    _Pragma("unroll") for (int mi = 0; mi < 4; ++mi)                                 \
        _Pragma("unroll") for (int ni = 0; ni < 2; ++ni)                             \
            _Pragma("unroll") for (int kk = 0; kk < 2; ++kk)                         \
                acc[mi + 4][ni + 2] = __builtin_amdgcn_mfma_f32_16x16x32_bf16(af[mi][kk], b23[ni][kk], acc[mi + 4][ni + 2], 0, 0, 0); \
    __builtin_amdgcn_s_setprio(0);                                                   \
    __builtin_amdgcn_s_barrier();                                                    \
    /* ---- phase 3: no ds reads, stage B-half1(T+2), boundary vmcnt ---- */         \
    if (SB) { STG(Bsrc, ldsBt + (CB) * 65536, 1, KTB) }                              \
    __builtin_amdgcn_s_barrier();                                                    \
    __builtin_amdgcn_s_setprio(1);                                                   \
    _Pragma("unroll") for (int mi = 0; mi < 4; ++mi)                                 \
        _Pragma("unroll") for (int ni = 0; ni < 2; ++ni)                             \
            _Pragma("unroll") for (int kk = 0; kk < 2; ++kk)                         \
                acc[mi + 4][ni] = __builtin_amdgcn_mfma_f32_16x16x32_bf16(af[mi][kk], b01[ni][kk], acc[mi + 4][ni], 0, 0, 0); \
    __builtin_amdgcn_s_setprio(0);                                                   \
    asm volatile("s_waitcnt vmcnt(" #VM ")" ::: "memory");                           \
    __builtin_amdgcn_s_barrier();                                                    \
} while (0)

__global__ __launch_bounds__(512, 2) void gemm_bf16_256(
    const u16* __restrict__ A, const u16* __restrict__ Bt, float* __restrict__ C) {
    __shared__ __align__(16) u16 sh[2][2][256][64];   // [buf][A/B][row][col] = 128 KiB
    char* shb = (char*)&sh[0][0][0][0];

    const int t = threadIdx.x;
    const int lane = t & 63;
    const int wid = t >> 6;
    const int wr = wid >> 2;   // 0..1
    const int wc = wid & 3;    // 0..3

    // T1: bijective XCD swizzle (512 wgs, 512 % 8 == 0)
    const int bid = blockIdx.x;
    const int wg = (bid & 7) * 64 + (bid >> 3);
    const int tm = wg >> 4;          // 0..31  (N/256 = 16 tiles per row)
    const int tn = wg & 15;          // 0..15

    // staging source (pre-swizzled column: col ^= 16 bf16 when dest row&4)
    const int srow = t >> 3;                                   // 0..63
    const int scol = ((t & 7) * 8) ^ (((t >> 5) & 1) << 4);    // bf16 units
    const u16* Asrc = A + (long)(tm * 256 + srow) * GK + scol;
    const u16* Bsrc = Bt + (long)(tn * 256 + srow) * GK + scol;
    char* ldsAt = shb + t * 16;            // + buf*65536 (+h*16384 +j*8192)
    char* ldsBt = shb + 32768 + t * 16;

    // ds_read lane addressing (same involution on read side)
    const int lrow = lane & 15;
    const int lcol = ((lane >> 4) * 16) ^ ((lane & 4) << 3);   // byte offset
    const int aoff = (wr * 128 + lrow) * 128 + lcol;
    const int boff = (wc * 64 + lrow) * 128 + lcol;

    f32x4 acc[8][4] = {};
    bf16x8 af[4][2], b01[2][2], b23[2][2];

    // prologue: B0(0) B1(0) A0(0) A1(0) B0(1) B1(1); allow last 2 half-tiles in flight
    STG(Bsrc, ldsBt, 0, 0)
    STG(Bsrc, ldsBt, 1, 0)
    STG(Asrc, ldsAt, 0, 0)
    STG(Asrc, ldsAt, 1, 0)
    STG(Bsrc, ldsBt + 65536, 0, 64)
    STG(Bsrc, ldsBt + 65536, 1, 64)
    asm volatile("s_waitcnt vmcnt(4)" ::: "memory");
    __builtin_amdgcn_s_barrier();

    // main loop: T = 0..61 (pairs), then T=62 (stage A(63) only), T=63 (no staging)
#pragma unroll 1
    for (int it = 0; it < 31; ++it) {
        const long kt = (long)it * 128;
        KTILE(0, 1, true, true, 4, kt + 64, kt + 128);
        KTILE(1, 0, true, true, 4, kt + 128, kt + 192);
    }
    KTILE(0, 1, true, false, 0, 4032, 0);
    KTILE(1, 0, false, false, 0, 0, 0);

    // epilogue: C/D layout col=lane&15, row=(lane>>4)*4+j
    const int crow = (lane >> 4) * 4;
    const int ccol = lane & 15;
    float* Cp = C + (long)(tm * 256 + wr * 128 + crow) * 4096 + tn * 256 + wc * 64 + ccol;
#pragma unroll
    for (int mi = 0; mi < 8; ++mi) {
#pragma unroll
        for (int j = 0; j < 4; ++j) {
            float* r = Cp + (long)(mi * 16 + j) * 4096;
#pragma unroll
            for (int ni = 0; ni < 4; ++ni)
                r[ni * 16] = acc[mi][ni][j];
        }
    }
}

// fallback (only if ws_size is too small): correct fp32 tiled GEMM
__global__ void gemm_f32_fallback(const float* __restrict__ A, const float* __restrict__ B,
                                  float* __restrict__ C, int M, int N, int K) {
    __shared__ float As[16][17];
    __shared__ float Bs[16][17];
    int tx = threadIdx.x & 15;
    int ty = threadIdx.x >> 4;
    int row = blockIdx.y * 16 + ty;
    int col = blockIdx.x * 16 + tx;
    float s = 0.f;
    for (int k0 = 0; k0 < K; k0 += 16) {
        As[ty][tx] = A[(long)row * K + k0 + tx];
        Bs[ty][tx] = B[(long)(k0 + ty) * N + col];
        __syncthreads();
#pragma unroll
        for (int kk = 0; kk < 16; ++kk) s += As[ty][kk] * Bs[kk][tx];
        __syncthreads();
    }
    C[(long)row * N + col] = s;
}

extern "C" void kernel_launch(void* const* d_in, const int* in_sizes, int n_in,
                              void* d_out, int out_size, void* d_ws, size_t ws_size,
                              hipStream_t stream) {
    const int M = 8192, K = 4096, N = 4096;
    const float* x = (const float*)d_in[0];       // [M][K] fp32
    const float* wte = (const float*)d_in[1];     // [K][N] fp32
    float* out = (float*)d_out;                   // [M][N] fp32

    const size_t need = (size_t)M * K * 2 + (size_t)K * N * 2;  // 96 MiB
    if (ws_size >= need) {
        u16* xb = (u16*)d_ws;                  // [M][K] bf16
        u16* wt = xb + (size_t)M * K;          // [N][K] bf16 (transposed)

        cvt_f32_to_bf16<<<2048, 256, 0, stream>>>(x, xb, (long)M * K / 8);

        dim3 tg(N / 32, K / 32);
        transpose_cvt<<<tg, 256, 0, stream>>>(wte, wt, K, N);

        const int nblocks = (M / 256) * (N / 256);   // 512
        gemm_bf16_256<<<nblocks, 512, 0, stream>>>(xb, wt, out);
    } else {
        dim3 g(N / 16, M / 16);
        gemm_f32_fallback<<<g, 256, 0, stream>>>(x, wte, out, M, N, K);
    }
}

// Round 3
// 269.722 us; speedup vs baseline: 1.4802x; 1.0677x over previous
//
#include <hip/hip_runtime.h>
#include <hip/hip_bf16.h>

typedef unsigned short u16;
typedef __bf16 bf16x8 __attribute__((ext_vector_type(8)));
typedef float f32x4 __attribute__((ext_vector_type(4)));

static __device__ __forceinline__ u16 f2b(float f) {
    __hip_bfloat16 h = __float2bfloat16(f);
    union { __hip_bfloat16 b; u16 u; } c;
    c.b = h;
    return c.u;
}

// fp32 -> bf16 bits, 8 elements per thread-iter
__global__ void cvt_f32_to_bf16(const float* __restrict__ in, u16* __restrict__ out, long n8) {
    long i = (long)blockIdx.x * blockDim.x + threadIdx.x;
    long stride = (long)gridDim.x * blockDim.x;
    for (long v = i; v < n8; v += stride) {
        const float4* p = reinterpret_cast<const float4*>(in) + 2 * v;
        float4 a = p[0];
        float4 b = p[1];
        uint4 o;
        o.x = (unsigned)f2b(a.x) | ((unsigned)f2b(a.y) << 16);
        o.y = (unsigned)f2b(a.z) | ((unsigned)f2b(a.w) << 16);
        o.z = (unsigned)f2b(b.x) | ((unsigned)f2b(b.y) << 16);
        o.w = (unsigned)f2b(b.z) | ((unsigned)f2b(b.w) << 16);
        reinterpret_cast<uint4*>(out)[v] = o;
    }
}

// W[K][N] fp32 -> Wt[N][K] bf16 bits, 32x32 LDS-tiled transpose
__global__ void transpose_cvt(const float* __restrict__ w, u16* __restrict__ wt, int K, int N) {
    __shared__ float tile[32][33];
    int bn = blockIdx.x * 32;
    int bk = blockIdx.y * 32;
    int tx = threadIdx.x & 31;
    int ty = threadIdx.x >> 5;
#pragma unroll
    for (int i = 0; i < 32; i += 8)
        tile[ty + i][tx] = w[(long)(bk + ty + i) * N + bn + tx];
    __syncthreads();
#pragma unroll
    for (int i = 0; i < 32; i += 8)
        wt[(long)(bn + ty + i) * K + bk + tx] = f2b(tile[tx][ty + i]);
}

static __device__ __forceinline__ void gl_lds16(const u16* g, u16* l) {
    __builtin_amdgcn_global_load_lds(
        (const __attribute__((address_space(1))) void*)g,
        (__attribute__((address_space(3))) void*)l, 16, 0, 0);
}

// ---------------------------------------------------------------------------
// 256x256 8-phase bf16 GEMM (T1+T2+T3/T4+T5), C = A[8192][4096] * Wt[4096][4096]^T
// 512 threads = 8 waves (2M x 4N), per-wave 128x64 output, BK=64, K-tiles NT=64.
// LDS: 2 buf x (A[256][64] | B[256][64]) bf16 = 128 KiB.
// T2 swizzle (full 3-bit, G4): physical colblk(16B) = logical ^ (row&7).
//   - staging: global SOURCE col pre-permuted (LDS dest stays linear: rule #21)
//   - ds_read: col byte = ((lane>>4)^(row&7))<<4, K-half bit folded via ^(kk<<6)
// Staging: per phase 1 half-tile (2 x global_load_lds w16). A staged T+1,
// B staged T+2; boundary s_waitcnt vmcnt(4), vmcnt(0) only entering last tile.
// ---------------------------------------------------------------------------
#define GK 4096L

#define STG(srcbase, dstbase, hh, ktel)                                              \
    gl_lds16((srcbase) + (long)((hh) * 128) * GK + (ktel), (u16*)((dstbase) + (hh) * 16384)); \
    gl_lds16((srcbase) + (long)((hh) * 128 + 64) * GK + (ktel), (u16*)((dstbase) + (hh) * 16384 + 8192));

#define KTILE(CB, OB, SA, SB, VM, KTA, KTB) do {                                     \
    char* cb = shb + (CB) * 65536;                                                   \
    /* ---- phase 0: read A m0-3 + B n0-1 (12 ds), stage A-half0(T+1) ---- */        \
    _Pragma("unroll") for (int mi = 0; mi < 4; ++mi)                                 \
        _Pragma("unroll") for (int kk = 0; kk < 2; ++kk)                             \
            af[mi][kk] = *(const bf16x8*)(cb + abase + mi * 2048 + (lcol ^ (kk * 64))); \
    _Pragma("unroll") for (int ni = 0; ni < 2; ++ni)                                 \
        _Pragma("unroll") for (int kk = 0; kk < 2; ++kk)                             \
            b01[ni][kk] = *(const bf16x8*)(cb + bbase + ni * 2048 + (lcol ^ (kk * 64))); \
    if (SA) { STG(Asrc, ldsAt + (OB) * 65536, 0, KTA) }                              \
    __builtin_amdgcn_s_barrier();                                                    \
    asm volatile("s_waitcnt lgkmcnt(0)");                                            \
    __builtin_amdgcn_s_setprio(1);                                                   \
    _Pragma("unroll") for (int mi = 0; mi < 4; ++mi)                                 \
        _Pragma("unroll") for (int ni = 0; ni < 2; ++ni)                             \
            _Pragma("unroll") for (int kk = 0; kk < 2; ++kk)                         \
                acc[mi][ni] = __builtin_amdgcn_mfma_f32_16x16x32_bf16(af[mi][kk], b01[ni][kk], acc[mi][ni], 0, 0, 0); \
    __builtin_amdgcn_s_setprio(0);                                                   \
    __builtin_amdgcn_s_barrier();                                                    \
    /* ---- phase 1: read B n2-3 (4 ds), stage A-half1(T+1) ---- */                  \
    _Pragma("unroll") for (int ni = 0; ni < 2; ++ni)                                 \
        _Pragma("unroll") for (int kk = 0; kk < 2; ++kk)                             \
            b23[ni][kk] = *(const bf16x8*)(cb + bbase + (ni + 2) * 2048 + (lcol ^ (kk * 64))); \
    if (SA) { STG(Asrc, ldsAt + (OB) * 65536, 1, KTA) }                              \
    __builtin_amdgcn_s_barrier();                                                    \
    asm volatile("s_waitcnt lgkmcnt(0)");                                            \
    __builtin_amdgcn_s_setprio(1);                                                   \
    _Pragma("unroll") for (int mi = 0; mi < 4; ++mi)                                 \
        _Pragma("unroll") for (int ni = 0; ni < 2; ++ni)                             \
            _Pragma("unroll") for (int kk = 0; kk < 2; ++kk)                         \
                acc[mi][ni + 2] = __builtin_amdgcn_mfma_f32_16x16x32_bf16(af[mi][kk], b23[ni][kk], acc[mi][ni + 2], 0, 0, 0); \
    __builtin_amdgcn_s_setprio(0);                                                   \
    __builtin_amdgcn_s_barrier();                                                    \
    /* ---- phase 2: read A m4-7 (8 ds), stage B-half0(T+2) ---- */                  \
    _Pragma("unroll") for (int mi = 0; mi < 4; ++mi)                                 \
        _Pragma("unroll") for (int kk = 0; kk < 2; ++kk)                             \
            af[mi][kk] = *(const bf16x8*)(cb + abase + (mi + 4) * 2048 + (lcol ^ (kk * 64))); \
    if (SB) { STG(Bsrc, ldsBt + (CB) * 65536, 0, KTB) }                              \
    __builtin_amdgcn_s_barrier();                                                    \
    asm volatile("s_waitcnt lgkmcnt(0)");                                            \
    __builtin_amdgcn_s_setprio(1);                                                   \
    _Pragma("unroll") for (int mi = 0; mi < 4; ++mi)                                 \
        _Pragma("unroll") for (int ni = 0; ni < 2; ++ni)                             \
            _Pragma("unroll") for (int kk = 0; kk < 2; ++kk)                         \
                acc[mi + 4][ni + 2] = __builtin_amdgcn_mfma_f32_16x16x32_bf16(af[mi][kk], b23[ni][kk], acc[mi + 4][ni + 2], 0, 0, 0); \
    __builtin_amdgcn_s_setprio(0);                                                   \
    __builtin_amdgcn_s_barrier();                                                    \
    /* ---- phase 3: no ds reads, stage B-half1(T+2), boundary vmcnt ---- */         \
    if (SB) { STG(Bsrc, ldsBt + (CB) * 65536, 1, KTB) }                              \
    __builtin_amdgcn_s_barrier();                                                    \
    __builtin_amdgcn_s_setprio(1);                                                   \
    _Pragma("unroll") for (int mi = 0; mi < 4; ++mi)                                 \
        _Pragma("unroll") for (int ni = 0; ni < 2; ++ni)                             \
            _Pragma("unroll") for (int kk = 0; kk < 2; ++kk)                         \
                acc[mi + 4][ni] = __builtin_amdgcn_mfma_f32_16x16x32_bf16(af[mi][kk], b01[ni][kk], acc[mi + 4][ni], 0, 0, 0); \
    __builtin_amdgcn_s_setprio(0);                                                   \
    asm volatile("s_waitcnt vmcnt(" #VM ")" ::: "memory");                           \
    __builtin_amdgcn_s_barrier();                                                    \
} while (0)

__global__ __launch_bounds__(512, 2) void gemm_bf16_256(
    const u16* __restrict__ A, const u16* __restrict__ Bt, float* __restrict__ C) {
    __shared__ __align__(16) u16 sh[2][2][256][64];   // [buf][A/B][row][col] = 128 KiB
    char* shb = (char*)&sh[0][0][0][0];

    const int t = threadIdx.x;
    const int lane = t & 63;
    const int wid = t >> 6;
    const int wr = wid >> 2;   // 0..1
    const int wc = wid & 3;    // 0..3

    // T1: bijective XCD swizzle (512 wgs, 512 % 8 == 0)
    const int bid = blockIdx.x;
    const int wg = (bid & 7) * 64 + (bid >> 3);
    const int tm = wg >> 4;          // 0..31  (N/256 = 16 tiles per row)
    const int tn = wg & 15;          // 0..15

    // staging source: thread t -> LDS physical (row = t>>3, colblk = t&7).
    // physical colblk holds logical colblk (t&7) ^ (row&7)  [T2 involution]
    const int srow = t >> 3;                                         // 0..63
    const int scol = (((t & 7) ^ ((t >> 3) & 7)) * 8);               // bf16 units
    const u16* Asrc = A + (long)(tm * 256 + srow) * GK + scol;
    const u16* Bsrc = Bt + (long)(tn * 256 + srow) * GK + scol;
    char* ldsAt = shb + t * 16;            // + buf*65536 (+h*16384 +j*8192)
    char* ldsBt = shb + 32768 + t * 16;

    // ds_read lane addressing: same involution; kk folds in via ^(kk<<6)
    const int lrow = lane & 15;
    const int lcol = (((lane >> 4) ^ (lrow & 7)) << 4);              // byte offset
    const int abase = (wr * 128 + lrow) * 128;
    const int bbase = 32768 + (wc * 64 + lrow) * 128;

    f32x4 acc[8][4] = {};
    bf16x8 af[4][2], b01[2][2], b23[2][2];

    // prologue: B0(0) B1(0) A0(0) A1(0) B0(1) B1(1); allow last 2 half-tiles in flight
    STG(Bsrc, ldsBt, 0, 0)
    STG(Bsrc, ldsBt, 1, 0)
    STG(Asrc, ldsAt, 0, 0)
    STG(Asrc, ldsAt, 1, 0)
    STG(Bsrc, ldsBt + 65536, 0, 64)
    STG(Bsrc, ldsBt + 65536, 1, 64)
    asm volatile("s_waitcnt vmcnt(4)" ::: "memory");
    __builtin_amdgcn_s_barrier();

    // main loop: T = 0..61 (pairs), then T=62 (stage A(63) only), T=63 (no staging)
#pragma unroll 1
    for (int it = 0; it < 31; ++it) {
        const long kt = (long)it * 128;
        KTILE(0, 1, true, true, 4, kt + 64, kt + 128);
        KTILE(1, 0, true, true, 4, kt + 128, kt + 192);
    }
    KTILE(0, 1, true, false, 0, 4032, 0);
    KTILE(1, 0, false, false, 0, 0, 0);

    // epilogue: C/D layout col=lane&15, row=(lane>>4)*4+j
    const int crow = (lane >> 4) * 4;
    const int ccol = lane & 15;
    float* Cp = C + (long)(tm * 256 + wr * 128 + crow) * 4096 + tn * 256 + wc * 64 + ccol;
#pragma unroll
    for (int mi = 0; mi < 8; ++mi) {
#pragma unroll
        for (int j = 0; j < 4; ++j) {
            float* r = Cp + (long)(mi * 16 + j) * 4096;
#pragma unroll
            for (int ni = 0; ni < 4; ++ni)
                r[ni * 16] = acc[mi][ni][j];
        }
    }
}

// fallback (only if ws_size is too small): correct fp32 tiled GEMM
__global__ void gemm_f32_fallback(const float* __restrict__ A, const float* __restrict__ B,
                                  float* __restrict__ C, int M, int N, int K) {
    __shared__ float As[16][17];
    __shared__ float Bs[16][17];
    int tx = threadIdx.x & 15;
    int ty = threadIdx.x >> 4;
    int row = blockIdx.y * 16 + ty;
    int col = blockIdx.x * 16 + tx;
    float s = 0.f;
    for (int k0 = 0; k0 < K; k0 += 16) {
        As[ty][tx] = A[(long)row * K + k0 + tx];
        Bs[ty][tx] = B[(long)(k0 + ty) * N + col];
        __syncthreads();
#pragma unroll
        for (int kk = 0; kk < 16; ++kk) s += As[ty][kk] * Bs[kk][tx];
        __syncthreads();
    }
    C[(long)row * N + col] = s;
}

extern "C" void kernel_launch(void* const* d_in, const int* in_sizes, int n_in,
                              void* d_out, int out_size, void* d_ws, size_t ws_size,
                              hipStream_t stream) {
    const int M = 8192, K = 4096, N = 4096;
    const float* x = (const float*)d_in[0];       // [M][K] fp32
    const float* wte = (const float*)d_in[1];     // [K][N] fp32
    float* out = (float*)d_out;                   // [M][N] fp32

    const size_t need = (size_t)M * K * 2 + (size_t)K * N * 2;  // 96 MiB
    if (ws_size >= need) {
        u16* xb = (u16*)d_ws;                  // [M][K] bf16
        u16* wt = xb + (size_t)M * K;          // [N][K] bf16 (transposed)

        cvt_f32_to_bf16<<<2048, 256, 0, stream>>>(x, xb, (long)M * K / 8);

        dim3 tg(N / 32, K / 32);
        transpose_cvt<<<tg, 256, 0, stream>>>(wte, wt, K, N);

        const int nblocks = (M / 256) * (N / 256);   // 512
        gemm_bf16_256<<<nblocks, 512, 0, stream>>>(xb, wt, out);
    } else {
        dim3 g(N / 16, M / 16);
        gemm_f32_fallback<<<g, 256, 0, stream>>>(x, wte, out, M, N, K);
    }
}